// Round 5
// baseline (130.523 us; speedup 1.0000x reference)
//
#include <hip/hip_runtime.h>
#include <math.h>

#define NATOMS    128
#define NSEG      7875     // segments: i in [0,124], j in [i+2,126]
#define NSEG_PAD  8192
#define OUT_PER_B 16256    // 128*127 (row-major, diagonal skipped)
#define BLOCK     512      // fused-fallback block size

typedef float v2f __attribute__((ext_vector_type(2)));
__device__ __forceinline__ v2f mk2(float a, float b) { v2f r; r.x = a; r.y = b; return r; }

// ======================= scalar helpers (split path) =======================
struct F3 { float x, y, z; };
__device__ __forceinline__ F3 f3(float x, float y, float z) { F3 r; r.x = x; r.y = y; r.z = z; return r; }
__device__ __forceinline__ F3 fsub(F3 a, F3 b) { return f3(a.x - b.x, a.y - b.y, a.z - b.z); }
__device__ __forceinline__ F3 fcross(F3 a, F3 b) {
    return f3(a.y * b.z - a.z * b.y, a.z * b.x - a.x * b.z, a.x * b.y - a.y * b.x);
}
__device__ __forceinline__ float fdot(F3 a, F3 b) { return a.x * b.x + a.y * b.y + a.z * b.z; }
__device__ __forceinline__ float fclip1(float x) { return fminf(fmaxf(x, -1.f), 1.f); }

// 4-term branchless asin, A&S 4.4.45 (|err| <= 6.8e-5).
__device__ __forceinline__ float fast_asin(float x) {
    float a = fabsf(x);
    float p = -0.0187293f;
    p = p * a + 0.0742610f;
    p = p * a + -0.2121144f;
    p = p * a + 1.5707288f;
    float r = 1.57079632679f - __builtin_amdgcn_sqrtf(1.0f - a) * p;
    return copysignf(r, x);
}

__device__ __forceinline__ int seg_row_base(int i) { return 125 * i - (__umul24(i, i - 1) >> 1); }

// (i,j) from linear segment id s (sqrt seed + exact fixup); s must be < NSEG.
__device__ __forceinline__ void seed_ij(int s, int &i, int &j) {
    i = (int)((251.0f - __builtin_amdgcn_sqrtf(63001.0f - 8.0f * (float)s)) * 0.5f);
    i = max(i, 0);
    i += (seg_row_base(i + 1) <= s);
    i += (seg_row_base(i + 1) <= s);
    i -= (seg_row_base(i) > s);
    i -= (seg_row_base(i) > s);
    j = s - seg_row_base(i) + i + 2;
}

// =================== kernel 1: one thread = one segment ====================
// Pure scalar writhe. No carried state, no packing, ~50 VGPR, 2KB LDS ->
// high occupancy; no phase barriers. Sign via the exact identity
//   cross(p3-p2, p1-p0) . u0 = -(u3 x u2) . u0 = -n2 . u0.
__global__ __launch_bounds__(256) void writhe_seg(
    const float* __restrict__ xyz,   // (B, 128, 3)
    float*       __restrict__ ws)    // (B, 8192) segment writhes
{
    __shared__ float4 sp4[NATOMS];
    const int bid = blockIdx.x;
    const int b   = bid >> 5;        // 32 blocks per batch
    const int sb  = bid & 31;
    const int t   = threadIdx.x;

    if (t < NATOMS) {
        const float* src = xyz + (size_t)b * (3 * NATOMS) + 3 * t;
        sp4[t] = make_float4(src[0], src[1], src[2], 0.f);
    }
    __syncthreads();

    const int s = (sb << 8) | t;
    if (s >= NSEG) return;

    int i, j; seed_ij(s, i, j);

    float4 P0 = sp4[i], P1 = sp4[i + 1], P2 = sp4[j], P3 = sp4[j + 1];
    F3 p0 = f3(P0.x, P0.y, P0.z), p1 = f3(P1.x, P1.y, P1.z);
    F3 p2 = f3(P2.x, P2.y, P2.z), p3 = f3(P3.x, P3.y, P3.z);

    F3 u0 = fsub(p2, p0);
    F3 u1 = fsub(p3, p0);
    F3 u2 = fsub(p2, p1);
    F3 u3 = fsub(p3, p1);

    F3 n0 = fcross(u0, u1);
    F3 n1 = fcross(u1, u3);
    F3 n2 = fcross(u3, u2);
    F3 n3 = fcross(u2, u0);

    float q0 = fdot(n0, n0);
    float q1 = fdot(n1, n1);
    float q2 = fdot(n2, n2);
    float q3 = fdot(n3, n3);

    float c0 = fclip1(fdot(n0, n1) * __builtin_amdgcn_rsqf(q0 * q1));
    float c1 = fclip1(fdot(n1, n2) * __builtin_amdgcn_rsqf(q1 * q2));
    float c2 = fclip1(fdot(n2, n3) * __builtin_amdgcn_rsqf(q2 * q3));
    float c3 = fclip1(fdot(n3, n0) * __builtin_amdgcn_rsqf(q3 * q0));

    float sd = fdot(n2, u0);   // = -(reference sd); sign folded below
    float omega = fast_asin(c0) + fast_asin(c1) + fast_asin(c2) + fast_asin(c3);
    float sgn = (sd > 0.f) ? -1.f : ((sd < 0.f) ? 1.f : 0.f);

    ws[(size_t)b * NSEG_PAD + s] = omega * sgn * 0.15915494309189535f;
}

// ================ kernel 2: one thread = one output element ================
// k in [0, 16256): r = k/127 (exact magic mul), c' = k%127, c = c' + (c'>=r).
// Gathers 4 segment writhes (16.8MB table, L2/L3-resident) with SELECTS (not
// multiplies) so poisoned/unwritten slots are never mixed in.
__global__ __launch_bounds__(256) void writhe_gather(
    const float* __restrict__ ws,    // (B, 8192)
    float*       __restrict__ out)   // (B, 16256)
{
    const int bid = blockIdx.x;
    const int b   = bid >> 6;        // 64 blocks per batch
    const int k   = ((bid & 63) << 8) | threadIdx.x;
    if (k >= OUT_PER_B) return;

    const float* w = ws + (size_t)b * NSEG_PAD;

    const int r = (int)(((unsigned)k * 132105u) >> 24);
    int c = k - r * 127;
    c += (c >= r);
    const int a  = min(r, c);
    const int bb = max(r, c);

    // segment ids for (i,j) in {a-1,a} x {b-1,b}; s(i,j)=base(i)+j-i-2
    const int am1 = a - 1;
    const int s00 = 125 * am1 - ((am1 * (am1 - 1)) >> 1) + bb - a - 2;  // (a-1, b-1)
    const int s10 = s00 + 125 - a;                                      // (a,   b-1)

    const bool v00 = (a >= 1) && (a <= 125) && (bb >= a + 2);
    const bool v01 = (a >= 1) && (a <= 125) && (bb <= 126);
    const bool v10 = (a <= 124) && (bb >= a + 3);
    const bool v11 = (a <= 124) && (bb <= 126) && (bb >= a + 2);

    const int c00 = min(max(s00,     0), NSEG - 1);
    const int c01 = min(max(s00 + 1, 0), NSEG - 1);
    const int c10 = min(max(s10,     0), NSEG - 1);
    const int c11 = min(max(s10 + 1, 0), NSEG - 1);

    float sum = (v00 ? w[c00] : 0.0f) + (v01 ? w[c01] : 0.0f)
              + (v10 ? w[c10] : 0.0f) + (v11 ? w[c11] : 0.0f);

    __builtin_nontemporal_store(sum, out + (size_t)b * OUT_PER_B + k);
}

// ================== fused fallback (round-4, verified) =====================
struct P3p { v2f x, y, z; };
__device__ __forceinline__ P3p psub(P3p a, P3p b) { return {a.x - b.x, a.y - b.y, a.z - b.z}; }
__device__ __forceinline__ P3p pcross(P3p a, P3p b) {
    return {a.y * b.z - a.z * b.y, a.z * b.x - a.x * b.z, a.x * b.y - a.y * b.x};
}
__device__ __forceinline__ v2f pdot(P3p a, P3p b) { return a.x * b.x + a.y * b.y + a.z * b.z; }
__device__ __forceinline__ v2f prsq(v2f q) {
    v2f r; r.x = __builtin_amdgcn_rsqf(q.x); r.y = __builtin_amdgcn_rsqf(q.y); return r;
}
__device__ __forceinline__ v2f pclip1(v2f x) {
    return __builtin_elementwise_min(__builtin_elementwise_max(x, mk2(-1.f, -1.f)),
                                     mk2(1.f, 1.f));
}
__device__ __forceinline__ v2f fast_asin2(v2f x) {
    v2f a = __builtin_elementwise_abs(x);
    v2f p = mk2(-0.0187293f, -0.0187293f);
    p = p * a + mk2( 0.0742610f,  0.0742610f);
    p = p * a + mk2(-0.2121144f, -0.2121144f);
    p = p * a + mk2( 1.5707288f,  1.5707288f);
    v2f om = mk2(1.0f, 1.0f) - a;
    v2f sq; sq.x = __builtin_amdgcn_sqrtf(om.x); sq.y = __builtin_amdgcn_sqrtf(om.y);
    v2f r = mk2(1.57079632679f, 1.57079632679f) - sq * p;
    return __builtin_elementwise_copysign(r, x);
}
__device__ __forceinline__ P3p pack3(const float4 &a, const float4 &b) {
    return { mk2(a.x, b.x), mk2(a.y, b.y), mk2(a.z, b.z) };
}
__device__ __forceinline__ v2f seg_writhe_pair(unsigned pa, unsigned pb, const float4* sp4) {
    int jA = (int)(pa & 127u), iA = (int)(pa >> 7);
    int jB = (int)(pb & 127u), iB = (int)(pb >> 7);
    float4 A0 = sp4[iA], A1 = sp4[iA + 1], A2 = sp4[jA], A3 = sp4[jA + 1];
    float4 B0 = sp4[iB], B1 = sp4[iB + 1], B2 = sp4[jB], B3 = sp4[jB + 1];
    P3p p0 = pack3(A0, B0), p1 = pack3(A1, B1), p2 = pack3(A2, B2), p3 = pack3(A3, B3);
    P3p u0 = psub(p2, p0), u1 = psub(p3, p0), u2 = psub(p2, p1), u3 = psub(p3, p1);
    P3p n0 = pcross(u0, u1), n1 = pcross(u1, u3), n2 = pcross(u3, u2), n3 = pcross(u2, u0);
    v2f q0 = pdot(n0, n0), q1 = pdot(n1, n1), q2 = pdot(n2, n2), q3 = pdot(n3, n3);
    v2f c0 = pclip1(pdot(n0, n1) * prsq(q0 * q1));
    v2f c1 = pclip1(pdot(n1, n2) * prsq(q1 * q2));
    v2f c2 = pclip1(pdot(n2, n3) * prsq(q2 * q3));
    v2f c3 = pclip1(pdot(n3, n0) * prsq(q3 * q0));
    v2f sd = pdot(n2, u0);
    v2f omega = fast_asin2(c0) + fast_asin2(c1) + fast_asin2(c2) + fast_asin2(c3);
    v2f sgn;
    sgn.x = (sd.x > 0.f) ? -1.f : ((sd.x < 0.f) ? 1.f : 0.f);
    sgn.y = (sd.y > 0.f) ? -1.f : ((sd.y < 0.f) ? 1.f : 0.f);
    return omega * sgn * mk2(0.15915494309189535f, 0.15915494309189535f);
}

__global__ __launch_bounds__(BLOCK, 4) void writhe_fused(
    const float* __restrict__ xyz, float* __restrict__ out)
{
    __shared__ float4 sp4[NATOMS];
    __shared__ float  swr[NSEG_PAD];
    __shared__ unsigned short sidx[NSEG_PAD];
    const int b = blockIdx.x;
    const int t = threadIdx.x;
    if (t < 3 * NATOMS) {
        float v = xyz[(size_t)b * (3 * NATOMS) + t];
        int a = t / 3, c = t - 3 * a;
        ((float*)&sp4[a])[c] = v;
    }
    {
        int s = t * 16;
        if (s < NSEG) {
            int i, j; seed_ij(s, i, j);
            #pragma unroll
            for (int k = 0; k < 16; ++k) {
                if (s < NSEG) sidx[s] = (unsigned short)((i << 7) | j);
                ++s; ++j;
                if (j > 126) { ++i; j = i + 2; }
            }
        }
        if (t < NSEG_PAD - NSEG) sidx[NSEG + t] = (unsigned short)((124 << 7) | 126);
    }
    __syncthreads();
    #pragma unroll
    for (int g = 0; g < 4; ++g) {
        const int sA = g * 2048 + t;
        v2f w1 = seg_writhe_pair(sidx[sA],        sidx[sA + 512],  sp4);
        v2f w2 = seg_writhe_pair(sidx[sA + 1024], sidx[sA + 1536], sp4);
        swr[sA]        = w1.x;
        swr[sA + 512]  = w1.y;
        swr[sA + 1024] = w2.x;
        swr[sA + 1536] = w2.y;
    }
    __syncthreads();
    float* ob = out + (size_t)b * OUT_PER_B;
    for (int k = t; k < OUT_PER_B; k += BLOCK) {
        const int r = (int)(((unsigned)k * 132105u) >> 24);
        int c = k - r * 127;
        c += (c >= r);
        const int a  = min(r, c);
        const int bb = max(r, c);
        const int am1 = a - 1;
        const int s00 = 125 * am1 - ((am1 * (am1 - 1)) >> 1) + bb - a - 2;
        const int s10 = s00 + 125 - a;
        const bool v00 = (a >= 1) && (a <= 125) && (bb >= a + 2);
        const bool v01 = (a >= 1) && (a <= 125) && (bb <= 126);
        const bool v10 = (a <= 124) && (bb >= a + 3);
        const bool v11 = (a <= 124) && (bb <= 126) && (bb >= a + 2);
        const int c00 = min(max(s00,     0), NSEG - 1);
        const int c01 = min(max(s00 + 1, 0), NSEG - 1);
        const int c10 = min(max(s10,     0), NSEG - 1);
        const int c11 = min(max(s10 + 1, 0), NSEG - 1);
        float sum = (v00 ? swr[c00] : 0.0f) + (v01 ? swr[c01] : 0.0f)
                  + (v10 ? swr[c10] : 0.0f) + (v11 ? swr[c11] : 0.0f);
        __builtin_nontemporal_store(sum, ob + k);
    }
}

extern "C" void kernel_launch(void* const* d_in, const int* in_sizes, int n_in,
                              void* d_out, int out_size, void* d_ws, size_t ws_size,
                              hipStream_t stream) {
    const float* xyz = (const float*)d_in[0];
    float*       out = (float*)d_out;

    int B = in_sizes[0] / (NATOMS * 3);   // 512 for the reference shapes

    const size_t need = (size_t)B * NSEG_PAD * sizeof(float);   // 16.8 MB @ B=512
    if (d_ws != nullptr && ws_size >= need) {
        float* ws = (float*)d_ws;
        writhe_seg<<<B * 32, 256, 0, stream>>>(xyz, ws);
        writhe_gather<<<B * 64, 256, 0, stream>>>(ws, out);
    } else {
        writhe_fused<<<B, BLOCK, 0, stream>>>(xyz, out);
    }
}

// Round 6
// 91.844 us; speedup vs baseline: 1.4211x; 1.4211x over previous
//
#include <hip/hip_runtime.h>
#include <math.h>

#define NATOMS    128
#define NSEG      7875     // segments: i in [0,124], j in [i+2,126]
#define NSEG_PAD  8192     // padded so Phase A needs no predication
#define NPAIR     8128     // pairs (a,b), 0 <= a < b <= 127
#define OUT_PER_B 16256    // 128*127 (row-major, diagonal skipped)
#define BLOCK     512

typedef float v2f __attribute__((ext_vector_type(2)));
__device__ __forceinline__ v2f mk2(float a, float b) { v2f r; r.x = a; r.y = b; return r; }

struct P3 { v2f x, y, z; };
__device__ __forceinline__ P3 psub(P3 a, P3 b) { return {a.x - b.x, a.y - b.y, a.z - b.z}; }
__device__ __forceinline__ P3 pcross(P3 a, P3 b) {
    return {a.y * b.z - a.z * b.y, a.z * b.x - a.x * b.z, a.x * b.y - a.y * b.x};
}
__device__ __forceinline__ v2f pdot(P3 a, P3 b) { return a.x * b.x + a.y * b.y + a.z * b.z; }
__device__ __forceinline__ v2f prsq(v2f q) {
    v2f r; r.x = __builtin_amdgcn_rsqf(q.x); r.y = __builtin_amdgcn_rsqf(q.y); return r;
}
__device__ __forceinline__ v2f pclip1(v2f x) {
    return __builtin_elementwise_min(__builtin_elementwise_max(x, mk2(-1.f, -1.f)),
                                     mk2(1.f, 1.f));
}

// Packed 4-term branchless asin, A&S 4.4.45 (|err| <= 6.8e-5).
__device__ __forceinline__ v2f fast_asin2(v2f x) {
    v2f a = __builtin_elementwise_abs(x);
    v2f p = mk2(-0.0187293f, -0.0187293f);
    p = p * a + mk2( 0.0742610f,  0.0742610f);
    p = p * a + mk2(-0.2121144f, -0.2121144f);
    p = p * a + mk2( 1.5707288f,  1.5707288f);
    v2f om = mk2(1.0f, 1.0f) - a;
    v2f sq; sq.x = __builtin_amdgcn_sqrtf(om.x); sq.y = __builtin_amdgcn_sqrtf(om.y);
    v2f r = mk2(1.57079632679f, 1.57079632679f) - sq * p;
    return __builtin_elementwise_copysign(r, x);
}

__device__ __forceinline__ int seg_row_base(int i) { return 125 * i - (__umul24(i, i - 1) >> 1); }

__device__ __forceinline__ P3 pack3(const float4 &a, const float4 &b) {
    return { mk2(a.x, b.x), mk2(a.y, b.y), mk2(a.z, b.z) };
}

// Writhe for TWO packed segments (x-lane = pa, y-lane = pb). Coordinates from
// float4 LDS (1 ds_read_b128 per point per sub-lane). Sign via the exact
// identity  cross(p3-p2, p1-p0) . u0 = -(u3 x u2) . u0 = -n2 . u0.
__device__ __forceinline__ v2f seg_writhe_pair(unsigned pa, unsigned pb,
                                               const float4* sp4) {
    int jA = (int)(pa & 127u), iA = (int)(pa >> 7);
    int jB = (int)(pb & 127u), iB = (int)(pb >> 7);

    float4 A0 = sp4[iA], A1 = sp4[iA + 1], A2 = sp4[jA], A3 = sp4[jA + 1];
    float4 B0 = sp4[iB], B1 = sp4[iB + 1], B2 = sp4[jB], B3 = sp4[jB + 1];

    P3 p0 = pack3(A0, B0);
    P3 p1 = pack3(A1, B1);
    P3 p2 = pack3(A2, B2);
    P3 p3 = pack3(A3, B3);

    P3 u0 = psub(p2, p0);
    P3 u1 = psub(p3, p0);
    P3 u2 = psub(p2, p1);
    P3 u3 = psub(p3, p1);

    P3 n0 = pcross(u0, u1);
    P3 n1 = pcross(u1, u3);
    P3 n2 = pcross(u3, u2);
    P3 n3 = pcross(u2, u0);

    v2f q0 = pdot(n0, n0);
    v2f q1 = pdot(n1, n1);
    v2f q2 = pdot(n2, n2);
    v2f q3 = pdot(n3, n3);

    v2f c0 = pclip1(pdot(n0, n1) * prsq(q0 * q1));
    v2f c1 = pclip1(pdot(n1, n2) * prsq(q1 * q2));
    v2f c2 = pclip1(pdot(n2, n3) * prsq(q2 * q3));
    v2f c3 = pclip1(pdot(n3, n0) * prsq(q3 * q0));

    v2f sd = pdot(n2, u0);     // = -(reference sd); sign folded below
    v2f omega = fast_asin2(c0) + fast_asin2(c1) + fast_asin2(c2) + fast_asin2(c3);

    v2f sgn;
    sgn.x = (sd.x > 0.f) ? -1.f : ((sd.x < 0.f) ? 1.f : 0.f);
    sgn.y = (sd.y > 0.f) ? -1.f : ((sd.y < 0.f) ? 1.f : 0.f);

    return omega * sgn * mk2(0.15915494309189535f, 0.15915494309189535f);
}

// One block per batch. Structure identical to round 4 EXCEPT launch bounds.
//
// REGISTER CEILING (the round-3..5 discovery): __launch_bounds__'s 2nd arg
// behaves as min BLOCKS/CU here (measured: lb(512,4) -> VGPR_Count=64 =
// 512 phys / 8 waves-per-EU, with massive scratch spill: 183MB FETCH /
// 299MB WRITE on the round-3 kernel). The two-packed-chain Phase A body
// needs ~110-140 live VGPRs; at a 64 cap EVERY prior fused round spilled
// ~150MB+ to scratch, which is exactly the observed ~40us kernel time and
// why load-width/conflict changes moved nothing.
// lb(512,2): 2 blocks x 8 waves = 16 waves/CU = 4 waves/EU -> 128 VGPR cap
// (or 256 under waves/EU semantics). Either way: no spill. LDS 50.3KB keeps
// residency at 2-3 blocks/CU regardless.
__global__ __launch_bounds__(BLOCK, 2) void writhe_fused(
    const float* __restrict__ xyz,       // (B, 128, 3)
    float*       __restrict__ out)       // (B, 16256)
{
    __shared__ float4 sp4[NATOMS];
    __shared__ float  swr[NSEG_PAD];
    __shared__ unsigned short sidx[NSEG_PAD];

    const int b = blockIdx.x;
    const int t = threadIdx.x;

    if (t < 3 * NATOMS) {
        float v = xyz[(size_t)b * (3 * NATOMS) + t];
        int a = t / 3, c = t - 3 * a;
        ((float*)&sp4[a])[c] = v;
    }

    // ---------- Phase 0: build sidx (+ pad tail with a safe segment) ----------
    {
        int s = t * 16;
        if (s < NSEG) {
            int i = (int)((251.0f - __builtin_amdgcn_sqrtf(63001.0f - 8.0f * (float)s)) * 0.5f);
            i = max(i, 0);
            i += (seg_row_base(i + 1) <= s);
            i += (seg_row_base(i + 1) <= s);
            i -= (seg_row_base(i) > s);
            i -= (seg_row_base(i) > s);
            int j = s - seg_row_base(i) + i + 2;
            #pragma unroll
            for (int k = 0; k < 16; ++k) {
                if (s < NSEG) sidx[s] = (unsigned short)((i << 7) | j);
                ++s; ++j;
                if (j > 126) { ++i; j = i + 2; }
            }
        }
        if (t < NSEG_PAD - NSEG) sidx[NSEG + t] = (unsigned short)((124 << 7) | 126);
    }
    __syncthreads();

    // ---------- Phase A: packed-pair writhe, 2 chains x 4 iterations ----------
    #pragma unroll
    for (int g = 0; g < 4; ++g) {
        const int sA = g * 2048 + t;     // sA..sA+1536 < 8192: unconditional
        v2f w1 = seg_writhe_pair(sidx[sA],        sidx[sA + 512],  sp4);
        v2f w2 = seg_writhe_pair(sidx[sA + 1024], sidx[sA + 1536], sp4);
        swr[sA]        = w1.x;
        swr[sA + 512]  = w1.y;
        swr[sA + 1024] = w2.x;
        swr[sA + 1536] = w2.y;
    }
    __syncthreads();

    // ---------- Phase D: lane-consecutive gather + coalesced store ----------
    // k in [0, 16256): r = k/127 (exact magic mul), c' = k%127, c = c' + (c'>=r).
    // Lane l handles k = l + q*BLOCK: stride-1 swr addresses across lanes.
    float* ob = out + (size_t)b * OUT_PER_B;
    for (int k = t; k < OUT_PER_B; k += BLOCK) {
        const int r = (int)(((unsigned)k * 132105u) >> 24);
        int c = k - r * 127;
        c += (c >= r);
        const int a  = min(r, c);
        const int bb = max(r, c);

        // segment ids for (i,j) in {a-1,a} x {b-1,b}; s(i,j)=base(i)+j-i-2
        const int am1 = a - 1;
        const int s00 = 125 * am1 - ((am1 * (am1 - 1)) >> 1) + bb - a - 2;  // (a-1, b-1)
        const int s10 = s00 + 125 - a;                                      // (a,   b-1)

        const bool v00 = (a >= 1) && (a <= 125) && (bb >= a + 2);
        const bool v01 = (a >= 1) && (a <= 125) && (bb <= 126);
        const bool v10 = (a <= 124) && (bb >= a + 3);
        const bool v11 = (a <= 124) && (bb <= 126) && (bb >= a + 2);

        const int c00 = min(max(s00,     0), NSEG - 1);
        const int c01 = min(max(s00 + 1, 0), NSEG - 1);
        const int c10 = min(max(s10,     0), NSEG - 1);
        const int c11 = min(max(s10 + 1, 0), NSEG - 1);

        float sum = (v00 ? swr[c00] : 0.0f) + (v01 ? swr[c01] : 0.0f)
                  + (v10 ? swr[c10] : 0.0f) + (v11 ? swr[c11] : 0.0f);

        __builtin_nontemporal_store(sum, ob + k);
    }
}

extern "C" void kernel_launch(void* const* d_in, const int* in_sizes, int n_in,
                              void* d_out, int out_size, void* d_ws, size_t ws_size,
                              hipStream_t stream) {
    const float* xyz = (const float*)d_in[0];
    float*       out = (float*)d_out;

    int B = in_sizes[0] / (NATOMS * 3);   // 512 for the reference shapes
    writhe_fused<<<B, BLOCK, 0, stream>>>(xyz, out);
}